// Round 1
// baseline (563.272 us; speedup 1.0000x reference)
//
#include <hip/hip_runtime.h>
#include <math.h>

#define N_NODES 100000
#define F_IN    128
#define HC      128      // H*C
#define NH      4
#define SLOPE   0.2f

static __device__ __forceinline__ float leaky(float x) { return x > 0.f ? x : SLOPE * x; }

// ---------------------------------------------------------------------------
// K1: h = x @ W   (100000x128 @ 128x128, fp32 vector ALU)
// BM=64 rows/block, full K=128, full N=128. 256 threads, each computes 8x4.
// x tile staged transposed in LDS [k][row] (pad 66); W read from global (hot in L1/L2).
// ---------------------------------------------------------------------------
__global__ __launch_bounds__(256) void k_gemm(const float* __restrict__ x,
                                              const float* __restrict__ W,
                                              float* __restrict__ h)
{
    __shared__ float xs[128 * 66];   // [k][row], pad 66 to break write conflicts
    const int t  = threadIdx.x;
    const int r0 = blockIdx.x * 64;

    // stage x block transposed: 64 rows x 128 k
    for (int i = t; i < 2048; i += 256) {           // 2048 float4 slots
        int row = i >> 5, kq = i & 31;
        int gr = r0 + row;
        float4 v = make_float4(0.f, 0.f, 0.f, 0.f);
        if (gr < N_NODES) v = ((const float4*)(x + (size_t)gr * F_IN))[kq];
        xs[(4 * kq + 0) * 66 + row] = v.x;
        xs[(4 * kq + 1) * 66 + row] = v.y;
        xs[(4 * kq + 2) * 66 + row] = v.z;
        xs[(4 * kq + 3) * 66 + row] = v.w;
    }
    __syncthreads();

    const int cg = t & 31;   // col group: cols 4cg..4cg+3
    const int rg = t >> 5;   // row group: rows rg*8..rg*8+7

    float acc[8][4];
    #pragma unroll
    for (int r = 0; r < 8; ++r)
        for (int c = 0; c < 4; ++c) acc[r][c] = 0.f;

    #pragma unroll 4
    for (int k = 0; k < 128; ++k) {
        float4 wv = *(const float4*)&W[k * HC + 4 * cg];
        #pragma unroll
        for (int r = 0; r < 8; ++r) {
            float xv = xs[k * 66 + rg * 8 + r];   // broadcast within half-wave
            acc[r][0] += xv * wv.x;
            acc[r][1] += xv * wv.y;
            acc[r][2] += xv * wv.z;
            acc[r][3] += xv * wv.w;
        }
    }

    #pragma unroll
    for (int r = 0; r < 8; ++r) {
        int gr = r0 + rg * 8 + r;
        if (gr < N_NODES)
            *(float4*)&h[(size_t)gr * HC + 4 * cg] =
                make_float4(acc[r][0], acc[r][1], acc[r][2], acc[r][3]);
    }
}

// ---------------------------------------------------------------------------
// K2: a_src[n][h] = sum_c h[n,h,c]*att_src[h,c]; same for a_dst.
// One wave per node; lane l owns channels 2l,2l+1; head = l>>4.
// ---------------------------------------------------------------------------
__global__ __launch_bounds__(256) void k_att(const float* __restrict__ h,
                                             const float* __restrict__ att_src,
                                             const float* __restrict__ att_dst,
                                             float* __restrict__ a_src,
                                             float* __restrict__ a_dst)
{
    const int lane = threadIdx.x & 63;
    const int node = blockIdx.x * 4 + (threadIdx.x >> 6);
    if (node >= N_NODES) return;

    float2 hv  = *(const float2*)&h[(size_t)node * HC + 2 * lane];
    float2 asv = *(const float2*)&att_src[2 * lane];
    float2 adv = *(const float2*)&att_dst[2 * lane];
    float ps = hv.x * asv.x + hv.y * asv.y;
    float pd = hv.x * adv.x + hv.y * adv.y;
    // reduce within 16-lane group (= one head: 32 channels)
    #pragma unroll
    for (int o = 1; o < 16; o <<= 1) {
        ps += __shfl_xor(ps, o);
        pd += __shfl_xor(pd, o);
    }
    if ((lane & 15) == 0) {
        a_src[node * NH + (lane >> 4)] = ps;
        a_dst[node * NH + (lane >> 4)] = pd;
    }
}

// ---------------------------------------------------------------------------
// K3: in-degree histogram over edges + self-loops
// ---------------------------------------------------------------------------
__global__ __launch_bounds__(256) void k_hist(const int* __restrict__ dstp,
                                              int* __restrict__ deg, int E)
{
    int i = blockIdx.x * 256 + threadIdx.x;
    int total = E + N_NODES;
    if (i < total) {
        int d = (i < E) ? dstp[i] : (i - E);
        atomicAdd(&deg[d], 1);
    }
}

// ---------------------------------------------------------------------------
// K4a/b/c: exclusive scan of deg -> rowptr (3-kernel, chunk=2048)
// ---------------------------------------------------------------------------
__global__ __launch_bounds__(256) void k_scan1(const int* __restrict__ deg,
                                               int* __restrict__ rowptr,
                                               int* __restrict__ bsum)
{
    __shared__ int sdata[256];
    const int b = blockIdx.x, t = threadIdx.x;
    const int base = b * 2048 + t * 8;
    int v[8];
    int sum = 0;
    #pragma unroll
    for (int j = 0; j < 8; ++j) {
        int idx = base + j;
        v[j] = (idx < N_NODES) ? deg[idx] : 0;
        sum += v[j];
    }
    sdata[t] = sum;
    __syncthreads();
    for (int o = 1; o < 256; o <<= 1) {
        int add = (t >= o) ? sdata[t - o] : 0;
        __syncthreads();
        sdata[t] += add;
        __syncthreads();
    }
    int excl = sdata[t] - sum;
    if (t == 255) bsum[b] = sdata[255];
    int run = excl;
    #pragma unroll
    for (int j = 0; j < 8; ++j) {
        int idx = base + j;
        if (idx < N_NODES) rowptr[idx] = run;
        run += v[j];
    }
}

__global__ void k_scan2(int* __restrict__ bsum, int nb)
{
    int lane = threadIdx.x;    // single wave of 64
    int v = (lane < nb) ? bsum[lane] : 0;
    int incl = v;
    #pragma unroll
    for (int o = 1; o < 64; o <<= 1) {
        int x = __shfl_up(incl, o);
        if (lane >= o) incl += x;
    }
    if (lane < nb) bsum[lane] = incl - v;   // exclusive
}

__global__ __launch_bounds__(256) void k_scan3(int* __restrict__ rowptr,
                                               int* __restrict__ cursor,
                                               const int* __restrict__ bsum,
                                               int total)
{
    int i = blockIdx.x * 256 + threadIdx.x;
    if (i == 0) rowptr[N_NODES] = total;
    if (i < N_NODES) {
        int vv = rowptr[i] + bsum[i >> 11];
        rowptr[i] = vv;
        cursor[i] = vv;
    }
}

// ---------------------------------------------------------------------------
// K5: scatter src indices into dst-grouped CSR col list
// ---------------------------------------------------------------------------
__global__ __launch_bounds__(256) void k_scatter(const int* __restrict__ srcp,
                                                 const int* __restrict__ dstp,
                                                 int* __restrict__ cursor,
                                                 int* __restrict__ col, int E)
{
    int i = blockIdx.x * 256 + threadIdx.x;
    int total = E + N_NODES;
    if (i < total) {
        int s = (i < E) ? srcp[i] : (i - E);
        int d = (i < E) ? dstp[i] : (i - E);
        int pos = atomicAdd(&cursor[d], 1);
        col[pos] = s;
    }
}

// ---------------------------------------------------------------------------
// K6: per-dst-node softmax + weighted aggregation. One wave per node.
// Lane l owns out channels 2l, 2l+1; head = l>>4.
// Phase 1: per-head max over incoming edges (lanes parallel over edges).
// Phase 2: wave-uniform loop over edges; coalesced 512B gather of h[src].
// ---------------------------------------------------------------------------
__global__ __launch_bounds__(256) void k_node(const float* __restrict__ h,
                                              const float* __restrict__ a_src,
                                              const float* __restrict__ a_dst,
                                              const int* __restrict__ rowptr,
                                              const int* __restrict__ col,
                                              const float* __restrict__ bias,
                                              float* __restrict__ out)
{
    const int lane = threadIdx.x & 63;
    const int node = blockIdx.x * 4 + (threadIdx.x >> 6);
    if (node >= N_NODES) return;

    const int r0 = rowptr[node];
    const int r1 = rowptr[node + 1];
    const float4 ad4 = *(const float4*)&a_dst[node * NH];

    // phase 1: per-head max of leaky(a_src[s]+a_dst[node])
    float m0 = -INFINITY, m1 = -INFINITY, m2 = -INFINITY, m3 = -INFINITY;
    for (int i = r0 + lane; i < r1; i += 64) {
        int s = col[i];
        float4 as4 = *(const float4*)&a_src[s * NH];
        m0 = fmaxf(m0, leaky(as4.x + ad4.x));
        m1 = fmaxf(m1, leaky(as4.y + ad4.y));
        m2 = fmaxf(m2, leaky(as4.z + ad4.z));
        m3 = fmaxf(m3, leaky(as4.w + ad4.w));
    }
    #pragma unroll
    for (int o = 32; o; o >>= 1) {
        m0 = fmaxf(m0, __shfl_xor(m0, o));
        m1 = fmaxf(m1, __shfl_xor(m1, o));
        m2 = fmaxf(m2, __shfl_xor(m2, o));
        m3 = fmaxf(m3, __shfl_xor(m3, o));
    }

    const int myh = lane >> 4;
    const float mm  = (myh == 0) ? m0 : (myh == 1) ? m1 : (myh == 2) ? m2 : m3;
    const float adm = (myh == 0) ? ad4.x : (myh == 1) ? ad4.y : (myh == 2) ? ad4.z : ad4.w;

    // phase 2: exp-weights + weighted sum of h[src]
    float denom = 0.f, acc0 = 0.f, acc1 = 0.f;
    for (int i = r0; i < r1; ++i) {
        int s = col[i];                         // wave-uniform
        float as = a_src[s * NH + myh];
        float e = leaky(as + adm);
        float p = __expf(e - mm);
        denom += p;
        float2 hv = *(const float2*)&h[(size_t)s * HC + 2 * lane];
        acc0 += p * hv.x;
        acc1 += p * hv.y;
    }

    float inv = 1.f / (denom + 1e-16f);
    float2 o2;
    o2.x = acc0 * inv + bias[2 * lane];
    o2.y = acc1 * inv + bias[2 * lane + 1];
    *(float2*)&out[(size_t)node * HC + 2 * lane] = o2;
}

// ---------------------------------------------------------------------------
extern "C" void kernel_launch(void* const* d_in, const int* in_sizes, int n_in,
                              void* d_out, int out_size, void* d_ws, size_t ws_size,
                              hipStream_t stream)
{
    const float* x       = (const float*)d_in[0];
    const float* W       = (const float*)d_in[1];
    const float* att_src = (const float*)d_in[2];
    const float* att_dst = (const float*)d_in[3];
    const float* bias    = (const float*)d_in[4];
    const int*   ei      = (const int*)d_in[5];
    const int E = in_sizes[5] / 2;
    const int* srcp = ei;
    const int* dstp = ei + E;
    float* out = (float*)d_out;

    char* wsb = (char*)d_ws;
    size_t off = 0;
    auto alloc = [&](size_t bytes) -> char* {
        char* p = wsb + off;
        off += (bytes + 255) & ~(size_t)255;
        return p;
    };
    float* h      = (float*)alloc((size_t)N_NODES * HC * sizeof(float));   // 51.2 MB
    float* a_src  = (float*)alloc((size_t)N_NODES * NH * sizeof(float));
    float* a_dst  = (float*)alloc((size_t)N_NODES * NH * sizeof(float));
    int*   deg    = (int*)alloc((size_t)N_NODES * sizeof(int));
    int*   rowptr = (int*)alloc((size_t)(N_NODES + 1) * sizeof(int));
    int*   cursor = (int*)alloc((size_t)N_NODES * sizeof(int));
    int*   bsum   = (int*)alloc(64 * sizeof(int));
    int*   col    = (int*)alloc((size_t)(E + N_NODES) * sizeof(int));      // 6.8 MB

    const int total = E + N_NODES;

    hipMemsetAsync(deg, 0, (size_t)N_NODES * sizeof(int), stream);

    k_gemm<<<(N_NODES + 63) / 64, 256, 0, stream>>>(x, W, h);
    k_att<<<(N_NODES + 3) / 4, 256, 0, stream>>>(h, att_src, att_dst, a_src, a_dst);
    k_hist<<<(total + 255) / 256, 256, 0, stream>>>(dstp, deg, E);
    k_scan1<<<49, 256, 0, stream>>>(deg, rowptr, bsum);
    k_scan2<<<1, 64, 0, stream>>>(bsum, 49);
    k_scan3<<<(N_NODES + 255) / 256, 256, 0, stream>>>(rowptr, cursor, bsum, total);
    k_scatter<<<(total + 255) / 256, 256, 0, stream>>>(srcp, dstp, cursor, col, E);
    k_node<<<(N_NODES + 3) / 4, 256, 0, stream>>>(h, a_src, a_dst, rowptr, col, bias, out);
}

// Round 2
// 489.381 us; speedup vs baseline: 1.1510x; 1.1510x over previous
//
#include <hip/hip_runtime.h>
#include <math.h>

#define N_NODES 100000
#define F_IN    128
#define HC      128      // H*C
#define NH      4
#define SLOPE   0.2f

static __device__ __forceinline__ float leaky(float x) { return x > 0.f ? x : SLOPE * x; }

// ---------------------------------------------------------------------------
// K1: h = x @ W   (100000x128 @ 128x128, fp32 vector ALU)
// BM=64 rows/block. 256 threads, each computes 8 rows x 4 cols.
// Epilogue fused: a_src/a_dst per (node, head) via 8-lane shfl reduction.
// ---------------------------------------------------------------------------
__global__ __launch_bounds__(256) void k_gemm(const float* __restrict__ x,
                                              const float* __restrict__ W,
                                              const float* __restrict__ att_src,
                                              const float* __restrict__ att_dst,
                                              float* __restrict__ h,
                                              float* __restrict__ a_src,
                                              float* __restrict__ a_dst)
{
    __shared__ float xs[128 * 66];   // [k][row], pad 66 to break write conflicts
    const int t  = threadIdx.x;
    const int r0 = blockIdx.x * 64;

    // stage x block transposed: 64 rows x 128 k
    for (int i = t; i < 2048; i += 256) {           // 2048 float4 slots
        int row = i >> 5, kq = i & 31;
        int gr = r0 + row;
        float4 v = make_float4(0.f, 0.f, 0.f, 0.f);
        if (gr < N_NODES) v = ((const float4*)(x + (size_t)gr * F_IN))[kq];
        xs[(4 * kq + 0) * 66 + row] = v.x;
        xs[(4 * kq + 1) * 66 + row] = v.y;
        xs[(4 * kq + 2) * 66 + row] = v.z;
        xs[(4 * kq + 3) * 66 + row] = v.w;
    }
    __syncthreads();

    const int cg = t & 31;   // col group: cols 4cg..4cg+3
    const int rg = t >> 5;   // row group: rows rg*8..rg*8+7

    float acc[8][4];
    #pragma unroll
    for (int r = 0; r < 8; ++r)
        for (int c = 0; c < 4; ++c) acc[r][c] = 0.f;

    #pragma unroll 4
    for (int k = 0; k < 128; ++k) {
        float4 wv = *(const float4*)&W[k * HC + 4 * cg];
        #pragma unroll
        for (int r = 0; r < 8; ++r) {
            float xv = xs[k * 66 + rg * 8 + r];   // broadcast within half-wave
            acc[r][0] += xv * wv.x;
            acc[r][1] += xv * wv.y;
            acc[r][2] += xv * wv.z;
            acc[r][3] += xv * wv.w;
        }
    }

    // store h
    #pragma unroll
    for (int r = 0; r < 8; ++r) {
        int gr = r0 + rg * 8 + r;
        if (gr < N_NODES)
            *(float4*)&h[(size_t)gr * HC + 4 * cg] =
                make_float4(acc[r][0], acc[r][1], acc[r][2], acc[r][3]);
    }

    // fused epilogue: a_src/a_dst. This thread's 4 cols live in head cg>>3,
    // channels (cg&7)*4 .. +3. Reduce over the 8-lane cg-group (lane bits 0..2).
    const int head = cg >> 3;
    const float4 atts = *(const float4*)&att_src[head * 32 + (cg & 7) * 4];
    const float4 attd = *(const float4*)&att_dst[head * 32 + (cg & 7) * 4];
    #pragma unroll
    for (int r = 0; r < 8; ++r) {
        float ps = acc[r][0] * atts.x + acc[r][1] * atts.y +
                   acc[r][2] * atts.z + acc[r][3] * atts.w;
        float pd = acc[r][0] * attd.x + acc[r][1] * attd.y +
                   acc[r][2] * attd.z + acc[r][3] * attd.w;
        ps += __shfl_xor(ps, 1); pd += __shfl_xor(pd, 1);
        ps += __shfl_xor(ps, 2); pd += __shfl_xor(pd, 2);
        ps += __shfl_xor(ps, 4); pd += __shfl_xor(pd, 4);
        int gr = r0 + rg * 8 + r;
        if ((cg & 7) == 0 && gr < N_NODES) {
            a_src[gr * NH + head] = ps;
            a_dst[gr * NH + head] = pd;
        }
    }
}

// ---------------------------------------------------------------------------
// K3: in-degree histogram over edges + self-loops
// ---------------------------------------------------------------------------
__global__ __launch_bounds__(256) void k_hist(const int* __restrict__ dstp,
                                              int* __restrict__ deg, int E)
{
    int i = blockIdx.x * 256 + threadIdx.x;
    int total = E + N_NODES;
    if (i < total) {
        int d = (i < E) ? dstp[i] : (i - E);
        atomicAdd(&deg[d], 1);
    }
}

// ---------------------------------------------------------------------------
// K4a/b/c: exclusive scan of deg -> rowptr (3-kernel, chunk=2048)
// ---------------------------------------------------------------------------
__global__ __launch_bounds__(256) void k_scan1(const int* __restrict__ deg,
                                               int* __restrict__ rowptr,
                                               int* __restrict__ bsum)
{
    __shared__ int sdata[256];
    const int b = blockIdx.x, t = threadIdx.x;
    const int base = b * 2048 + t * 8;
    int v[8];
    int sum = 0;
    #pragma unroll
    for (int j = 0; j < 8; ++j) {
        int idx = base + j;
        v[j] = (idx < N_NODES) ? deg[idx] : 0;
        sum += v[j];
    }
    sdata[t] = sum;
    __syncthreads();
    for (int o = 1; o < 256; o <<= 1) {
        int add = (t >= o) ? sdata[t - o] : 0;
        __syncthreads();
        sdata[t] += add;
        __syncthreads();
    }
    int excl = sdata[t] - sum;
    if (t == 255) bsum[b] = sdata[255];
    int run = excl;
    #pragma unroll
    for (int j = 0; j < 8; ++j) {
        int idx = base + j;
        if (idx < N_NODES) rowptr[idx] = run;
        run += v[j];
    }
}

__global__ void k_scan2(int* __restrict__ bsum, int nb)
{
    int lane = threadIdx.x;    // single wave of 64
    int v = (lane < nb) ? bsum[lane] : 0;
    int incl = v;
    #pragma unroll
    for (int o = 1; o < 64; o <<= 1) {
        int x = __shfl_up(incl, o);
        if (lane >= o) incl += x;
    }
    if (lane < nb) bsum[lane] = incl - v;   // exclusive
}

__global__ __launch_bounds__(256) void k_scan3(int* __restrict__ rowptr,
                                               int* __restrict__ cursor,
                                               const int* __restrict__ bsum,
                                               int total)
{
    int i = blockIdx.x * 256 + threadIdx.x;
    if (i == 0) rowptr[N_NODES] = total;
    if (i < N_NODES) {
        int vv = rowptr[i] + bsum[i >> 11];
        rowptr[i] = vv;
        cursor[i] = vv;
    }
}

// ---------------------------------------------------------------------------
// K5: scatter src indices into dst-grouped CSR col list
// ---------------------------------------------------------------------------
__global__ __launch_bounds__(256) void k_scatter(const int* __restrict__ srcp,
                                                 const int* __restrict__ dstp,
                                                 int* __restrict__ cursor,
                                                 int* __restrict__ col, int E)
{
    int i = blockIdx.x * 256 + threadIdx.x;
    int total = E + N_NODES;
    if (i < total) {
        int s = (i < E) ? srcp[i] : (i - E);
        int d = (i < E) ? dstp[i] : (i - E);
        int pos = atomicAdd(&cursor[d], 1);
        col[pos] = s;
    }
}

// ---------------------------------------------------------------------------
// K6: per-dst-node softmax + weighted aggregation. One wave per node.
// No max pass: e = leaky(a_src+a_dst) is O(±6), exp cannot overflow in fp32,
// and p/sum(p) is shift-invariant, so result matches the reference.
// Edge loop unrolled x4 for memory-level parallelism.
// ---------------------------------------------------------------------------
__global__ __launch_bounds__(256) void k_node(const float* __restrict__ h,
                                              const float* __restrict__ a_src,
                                              const float* __restrict__ a_dst,
                                              const int* __restrict__ rowptr,
                                              const int* __restrict__ col,
                                              const float* __restrict__ bias,
                                              float* __restrict__ out)
{
    const int lane = threadIdx.x & 63;
    const int node = blockIdx.x * 4 + (threadIdx.x >> 6);
    if (node >= N_NODES) return;

    const int r0 = rowptr[node];
    const int r1 = rowptr[node + 1];
    const int myh = lane >> 4;
    const float adm = a_dst[node * NH + myh];

    float denom = 0.f, acc0 = 0.f, acc1 = 0.f;
    int i = r0;
    for (; i + 4 <= r1; i += 4) {
        int s0 = col[i], s1 = col[i + 1], s2 = col[i + 2], s3 = col[i + 3];
        float as0 = a_src[s0 * NH + myh];
        float as1 = a_src[s1 * NH + myh];
        float as2 = a_src[s2 * NH + myh];
        float as3 = a_src[s3 * NH + myh];
        float2 h0 = *(const float2*)&h[(size_t)s0 * HC + 2 * lane];
        float2 h1 = *(const float2*)&h[(size_t)s1 * HC + 2 * lane];
        float2 h2 = *(const float2*)&h[(size_t)s2 * HC + 2 * lane];
        float2 h3 = *(const float2*)&h[(size_t)s3 * HC + 2 * lane];
        float p0 = __expf(leaky(as0 + adm));
        float p1 = __expf(leaky(as1 + adm));
        float p2 = __expf(leaky(as2 + adm));
        float p3 = __expf(leaky(as3 + adm));
        denom += (p0 + p1) + (p2 + p3);
        acc0 += p0 * h0.x; acc1 += p0 * h0.y;
        acc0 += p1 * h1.x; acc1 += p1 * h1.y;
        acc0 += p2 * h2.x; acc1 += p2 * h2.y;
        acc0 += p3 * h3.x; acc1 += p3 * h3.y;
    }
    for (; i < r1; ++i) {
        int s = col[i];
        float p = __expf(leaky(a_src[s * NH + myh] + adm));
        float2 hv = *(const float2*)&h[(size_t)s * HC + 2 * lane];
        denom += p;
        acc0 += p * hv.x; acc1 += p * hv.y;
    }

    float inv = 1.f / (denom + 1e-16f);
    float2 o2;
    o2.x = acc0 * inv + bias[2 * lane];
    o2.y = acc1 * inv + bias[2 * lane + 1];
    *(float2*)&out[(size_t)node * HC + 2 * lane] = o2;
}

// ---------------------------------------------------------------------------
extern "C" void kernel_launch(void* const* d_in, const int* in_sizes, int n_in,
                              void* d_out, int out_size, void* d_ws, size_t ws_size,
                              hipStream_t stream)
{
    const float* x       = (const float*)d_in[0];
    const float* W       = (const float*)d_in[1];
    const float* att_src = (const float*)d_in[2];
    const float* att_dst = (const float*)d_in[3];
    const float* bias    = (const float*)d_in[4];
    const int*   ei      = (const int*)d_in[5];
    const int E = in_sizes[5] / 2;
    const int* srcp = ei;
    const int* dstp = ei + E;
    float* out = (float*)d_out;

    char* wsb = (char*)d_ws;
    size_t off = 0;
    auto alloc = [&](size_t bytes) -> char* {
        char* p = wsb + off;
        off += (bytes + 255) & ~(size_t)255;
        return p;
    };
    float* h      = (float*)alloc((size_t)N_NODES * HC * sizeof(float));   // 51.2 MB
    float* a_src  = (float*)alloc((size_t)N_NODES * NH * sizeof(float));
    float* a_dst  = (float*)alloc((size_t)N_NODES * NH * sizeof(float));
    int*   deg    = (int*)alloc((size_t)N_NODES * sizeof(int));
    int*   rowptr = (int*)alloc((size_t)(N_NODES + 1) * sizeof(int));
    int*   cursor = (int*)alloc((size_t)N_NODES * sizeof(int));
    int*   bsum   = (int*)alloc(64 * sizeof(int));
    int*   col    = (int*)alloc((size_t)(E + N_NODES) * sizeof(int));      // 6.8 MB

    const int total = E + N_NODES;

    hipMemsetAsync(deg, 0, (size_t)N_NODES * sizeof(int), stream);

    k_gemm<<<(N_NODES + 63) / 64, 256, 0, stream>>>(x, W, att_src, att_dst,
                                                    h, a_src, a_dst);
    k_hist<<<(total + 255) / 256, 256, 0, stream>>>(dstp, deg, E);
    k_scan1<<<49, 256, 0, stream>>>(deg, rowptr, bsum);
    k_scan2<<<1, 64, 0, stream>>>(bsum, 49);
    k_scan3<<<(N_NODES + 255) / 256, 256, 0, stream>>>(rowptr, cursor, bsum, total);
    k_scatter<<<(total + 255) / 256, 256, 0, stream>>>(srcp, dstp, cursor, col, E);
    k_node<<<(N_NODES + 3) / 4, 256, 0, stream>>>(h, a_src, a_dst, rowptr, col, bias, out);
}

// Round 3
// 346.821 us; speedup vs baseline: 1.6241x; 1.4110x over previous
//
#include <hip/hip_runtime.h>
#include <math.h>

#define N_NODES 100000
#define F_IN    128
#define HC      128      // H*C
#define NH      4
#define SLOPE   0.2f

#define NB      196      // buckets = ceil(N/512)
#define BSH     9        // bucket shift: bucket = dst >> 9, local = dst & 511
#define CAP     10240    // per-bucket arena capacity (mean 8192, sigma ~90 -> 22 sigma)
#define CHUNK   8192     // edges per k_bucket block

static __device__ __forceinline__ float leaky(float x) { return x > 0.f ? x : SLOPE * x; }

// ---------------------------------------------------------------------------
// K1: h = x @ W (100000x128 @ 128x128, fp32). BM=64/block, 256 thr, 8x4 each.
// Epilogue fused: a_src/a_dst per (node, head) via 8-lane shfl reduction.
// ---------------------------------------------------------------------------
__global__ __launch_bounds__(256) void k_gemm(const float* __restrict__ x,
                                              const float* __restrict__ W,
                                              const float* __restrict__ att_src,
                                              const float* __restrict__ att_dst,
                                              float* __restrict__ h,
                                              float* __restrict__ a_src,
                                              float* __restrict__ a_dst)
{
    __shared__ float xs[128 * 66];
    const int t  = threadIdx.x;
    const int r0 = blockIdx.x * 64;

    for (int i = t; i < 2048; i += 256) {
        int row = i >> 5, kq = i & 31;
        int gr = r0 + row;
        float4 v = make_float4(0.f, 0.f, 0.f, 0.f);
        if (gr < N_NODES) v = ((const float4*)(x + (size_t)gr * F_IN))[kq];
        xs[(4 * kq + 0) * 66 + row] = v.x;
        xs[(4 * kq + 1) * 66 + row] = v.y;
        xs[(4 * kq + 2) * 66 + row] = v.z;
        xs[(4 * kq + 3) * 66 + row] = v.w;
    }
    __syncthreads();

    const int cg = t & 31;
    const int rg = t >> 5;

    float acc[8][4];
    #pragma unroll
    for (int r = 0; r < 8; ++r)
        for (int c = 0; c < 4; ++c) acc[r][c] = 0.f;

    #pragma unroll 4
    for (int k = 0; k < 128; ++k) {
        float4 wv = *(const float4*)&W[k * HC + 4 * cg];
        #pragma unroll
        for (int r = 0; r < 8; ++r) {
            float xv = xs[k * 66 + rg * 8 + r];
            acc[r][0] += xv * wv.x;
            acc[r][1] += xv * wv.y;
            acc[r][2] += xv * wv.z;
            acc[r][3] += xv * wv.w;
        }
    }

    #pragma unroll
    for (int r = 0; r < 8; ++r) {
        int gr = r0 + rg * 8 + r;
        if (gr < N_NODES)
            *(float4*)&h[(size_t)gr * HC + 4 * cg] =
                make_float4(acc[r][0], acc[r][1], acc[r][2], acc[r][3]);
    }

    const int head = cg >> 3;
    const float4 atts = *(const float4*)&att_src[head * 32 + (cg & 7) * 4];
    const float4 attd = *(const float4*)&att_dst[head * 32 + (cg & 7) * 4];
    #pragma unroll
    for (int r = 0; r < 8; ++r) {
        float ps = acc[r][0] * atts.x + acc[r][1] * atts.y +
                   acc[r][2] * atts.z + acc[r][3] * atts.w;
        float pd = acc[r][0] * attd.x + acc[r][1] * attd.y +
                   acc[r][2] * attd.z + acc[r][3] * attd.w;
        ps += __shfl_xor(ps, 1); pd += __shfl_xor(pd, 1);
        ps += __shfl_xor(ps, 2); pd += __shfl_xor(pd, 2);
        ps += __shfl_xor(ps, 4); pd += __shfl_xor(pd, 4);
        int gr = r0 + rg * 8 + r;
        if ((cg & 7) == 0 && gr < N_NODES) {
            a_src[gr * NH + head] = ps;
            a_dst[gr * NH + head] = pd;
        }
    }
}

// ---------------------------------------------------------------------------
// K2: multisplit edges into NB dst-buckets via LDS staging; dense flushes.
// eb[bucket*CAP + k] = (src<<9) | (dst&511). bucket_cursor[b] = count.
// Self-loops are NOT bucketed (k_csr injects them analytically).
// ---------------------------------------------------------------------------
__global__ __launch_bounds__(256) void k_bucket(const int* __restrict__ srcp,
                                                const int* __restrict__ dstp,
                                                int* __restrict__ bucket_cursor,
                                                int* __restrict__ eb, int E)
{
    __shared__ int ebuf[CHUNK];
    __shared__ unsigned char bkt[CHUNK];
    __shared__ int hist[256];        // counters, then rank cursors
    __shared__ int lexcl[257];
    __shared__ int gbase[256];
    __shared__ int sdata[256];

    const int t = threadIdx.x;
    const int base = blockIdx.x * CHUNK;

    hist[t] = 0;
    __syncthreads();

    // pass 1: histogram
    #pragma unroll
    for (int j = 0; j < CHUNK / 256; ++j) {
        int i = base + t + j * 256;
        if (i < E) atomicAdd(&hist[dstp[i] >> BSH], 1);
    }
    __syncthreads();

    // scan 256 counters (Hillis-Steele)
    int cnt = hist[t];
    sdata[t] = cnt;
    __syncthreads();
    for (int o = 1; o < 256; o <<= 1) {
        int add = (t >= o) ? sdata[t - o] : 0;
        __syncthreads();
        sdata[t] += add;
        __syncthreads();
    }
    int excl = sdata[t] - cnt;
    lexcl[t] = excl;
    if (t == 255) lexcl[256] = sdata[255];
    hist[t] = excl;                  // rank cursor
    int gb = 0;
    if (t < NB && cnt > 0) gb = atomicAdd(&bucket_cursor[t], cnt);
    gbase[t] = t * CAP + gb;
    __syncthreads();

    // pass 2: rank + stage in LDS
    #pragma unroll
    for (int j = 0; j < CHUNK / 256; ++j) {
        int i = base + t + j * 256;
        if (i < E) {
            int s = srcp[i], d = dstp[i];
            int b = d >> BSH;
            int r = atomicAdd(&hist[b], 1);
            ebuf[r] = (s << BSH) | (d & 511);
            bkt[r] = (unsigned char)b;
        }
    }
    __syncthreads();

    // flush: dense per-bucket runs
    const int blockTotal = lexcl[256];
    for (int i = t; i < blockTotal; i += 256) {
        int b = bkt[i];
        eb[gbase[b] + (i - lexcl[b])] = ebuf[i];
    }
}

// ---------------------------------------------------------------------------
// K3: tiny exclusive scan of bucket counts -> bexcl (compact col offsets).
// Counts include +512 self-loops per full bucket (added here analytically).
// ---------------------------------------------------------------------------
__global__ void k_bscan(const int* __restrict__ bucket_cursor,
                        int* __restrict__ bexcl)
{
    __shared__ int sdata[256];
    const int t = threadIdx.x;
    int nvalid = 0;
    if (t < NB) {
        int n0 = t * 512;
        nvalid = min(512, N_NODES - n0);
        if (nvalid < 0) nvalid = 0;
    }
    int v = (t < NB) ? bucket_cursor[t] + nvalid : 0;  // + self-loops
    sdata[t] = v;
    __syncthreads();
    for (int o = 1; o < 256; o <<= 1) {
        int add = (t >= o) ? sdata[t - o] : 0;
        __syncthreads();
        sdata[t] += add;
        __syncthreads();
    }
    if (t < NB) bexcl[t] = sdata[t] - v;
}

// ---------------------------------------------------------------------------
// K4: per-bucket CSR build. One block per bucket; cursor entirely in LDS.
// col writes confined to one contiguous region from one CU -> full lines.
// Self-loop injected at slot 0 of each node's segment.
// ---------------------------------------------------------------------------
__global__ __launch_bounds__(256) void k_csr(const int* __restrict__ eb,
                                             const int* __restrict__ bucket_cursor,
                                             const int* __restrict__ bexcl,
                                             int* __restrict__ col,
                                             int2* __restrict__ rowse)
{
    __shared__ int deg[512];
    __shared__ int sdata[256];

    const int t  = threadIdx.x;
    const int b  = blockIdx.x;
    const int n0 = b * 512;
    const int cnt   = bucket_cursor[b];
    const int ebase = b * CAP;
    const int gofs  = bexcl[b];

    deg[t]       = (n0 + t       < N_NODES) ? 1 : 0;   // self-loop
    deg[t + 256] = (n0 + t + 256 < N_NODES) ? 1 : 0;
    __syncthreads();

    for (int i = t; i < cnt; i += 256)
        atomicAdd(&deg[eb[ebase + i] & 511], 1);
    __syncthreads();

    // scan 512 (each thread owns 2)
    int d0 = deg[2 * t], d1 = deg[2 * t + 1];
    int ps = d0 + d1;
    sdata[t] = ps;
    __syncthreads();
    for (int o = 1; o < 256; o <<= 1) {
        int add = (t >= o) ? sdata[t - o] : 0;
        __syncthreads();
        sdata[t] += add;
        __syncthreads();
    }
    int e0 = sdata[t] - ps;
    int e1 = e0 + d0;
    __syncthreads();

    int na = n0 + 2 * t, nb2 = n0 + 2 * t + 1;
    if (na < N_NODES) {
        rowse[na] = make_int2(gofs + e0, gofs + e0 + d0);
        col[gofs + e0] = na;                 // self-loop
    }
    if (nb2 < N_NODES) {
        rowse[nb2] = make_int2(gofs + e1, gofs + e1 + d1);
        col[gofs + e1] = nb2;                // self-loop
    }
    deg[2 * t]     = e0 + 1;                 // cursor past self-loop
    deg[2 * t + 1] = e1 + 1;
    __syncthreads();

    for (int i = t; i < cnt; i += 256) {
        int v = eb[ebase + i];
        int r = atomicAdd(&deg[v & 511], 1);
        col[gofs + r] = v >> BSH;
    }
}

// ---------------------------------------------------------------------------
// K5: per-dst-node softmax + weighted aggregation. One wave per node.
// ---------------------------------------------------------------------------
__global__ __launch_bounds__(256) void k_node(const float* __restrict__ h,
                                              const float* __restrict__ a_src,
                                              const float* __restrict__ a_dst,
                                              const int2* __restrict__ rowse,
                                              const int* __restrict__ col,
                                              const float* __restrict__ bias,
                                              float* __restrict__ out)
{
    const int lane = threadIdx.x & 63;
    const int node = blockIdx.x * 4 + (threadIdx.x >> 6);
    if (node >= N_NODES) return;

    const int2 se = rowse[node];
    const int r0 = se.x, r1 = se.y;
    const int myh = lane >> 4;
    const float adm = a_dst[node * NH + myh];

    float denom = 0.f, acc0 = 0.f, acc1 = 0.f;
    int i = r0;
    for (; i + 4 <= r1; i += 4) {
        int s0 = col[i], s1 = col[i + 1], s2 = col[i + 2], s3 = col[i + 3];
        float as0 = a_src[s0 * NH + myh];
        float as1 = a_src[s1 * NH + myh];
        float as2 = a_src[s2 * NH + myh];
        float as3 = a_src[s3 * NH + myh];
        float2 h0 = *(const float2*)&h[(size_t)s0 * HC + 2 * lane];
        float2 h1 = *(const float2*)&h[(size_t)s1 * HC + 2 * lane];
        float2 h2 = *(const float2*)&h[(size_t)s2 * HC + 2 * lane];
        float2 h3 = *(const float2*)&h[(size_t)s3 * HC + 2 * lane];
        float p0 = __expf(leaky(as0 + adm));
        float p1 = __expf(leaky(as1 + adm));
        float p2 = __expf(leaky(as2 + adm));
        float p3 = __expf(leaky(as3 + adm));
        denom += (p0 + p1) + (p2 + p3);
        acc0 += p0 * h0.x; acc1 += p0 * h0.y;
        acc0 += p1 * h1.x; acc1 += p1 * h1.y;
        acc0 += p2 * h2.x; acc1 += p2 * h2.y;
        acc0 += p3 * h3.x; acc1 += p3 * h3.y;
    }
    for (; i < r1; ++i) {
        int s = col[i];
        float p = __expf(leaky(a_src[s * NH + myh] + adm));
        float2 hv = *(const float2*)&h[(size_t)s * HC + 2 * lane];
        denom += p;
        acc0 += p * hv.x; acc1 += p * hv.y;
    }

    float inv = 1.f / (denom + 1e-16f);
    float2 o2;
    o2.x = acc0 * inv + bias[2 * lane];
    o2.y = acc1 * inv + bias[2 * lane + 1];
    *(float2*)&out[(size_t)node * HC + 2 * lane] = o2;
}

// ---------------------------------------------------------------------------
extern "C" void kernel_launch(void* const* d_in, const int* in_sizes, int n_in,
                              void* d_out, int out_size, void* d_ws, size_t ws_size,
                              hipStream_t stream)
{
    const float* x       = (const float*)d_in[0];
    const float* W       = (const float*)d_in[1];
    const float* att_src = (const float*)d_in[2];
    const float* att_dst = (const float*)d_in[3];
    const float* bias    = (const float*)d_in[4];
    const int*   ei      = (const int*)d_in[5];
    const int E = in_sizes[5] / 2;
    const int* srcp = ei;
    const int* dstp = ei + E;
    float* out = (float*)d_out;

    char* wsb = (char*)d_ws;
    size_t off = 0;
    auto alloc = [&](size_t bytes) -> char* {
        char* p = wsb + off;
        off += (bytes + 255) & ~(size_t)255;
        return p;
    };
    float* h       = (float*)alloc((size_t)N_NODES * HC * sizeof(float));  // 51.2 MB
    float* a_src   = (float*)alloc((size_t)N_NODES * NH * sizeof(float));
    float* a_dst   = (float*)alloc((size_t)N_NODES * NH * sizeof(float));
    int*   eb      = (int*)alloc((size_t)NB * CAP * sizeof(int));          // 8.0 MB
    int*   col     = (int*)alloc((size_t)(E + N_NODES) * sizeof(int));     // 6.8 MB
    int2*  rowse   = (int2*)alloc((size_t)N_NODES * sizeof(int2));         // 0.8 MB
    int*   bcursor = (int*)alloc(256 * sizeof(int));
    int*   bexcl   = (int*)alloc(256 * sizeof(int));

    hipMemsetAsync(bcursor, 0, 256 * sizeof(int), stream);

    k_gemm<<<(N_NODES + 63) / 64, 256, 0, stream>>>(x, W, att_src, att_dst,
                                                    h, a_src, a_dst);
    k_bucket<<<(E + CHUNK - 1) / CHUNK, 256, 0, stream>>>(srcp, dstp, bcursor, eb, E);
    k_bscan<<<1, 256, 0, stream>>>(bcursor, bexcl);
    k_csr<<<NB, 256, 0, stream>>>(eb, bcursor, bexcl, col, rowse);
    k_node<<<(N_NODES + 3) / 4, 256, 0, stream>>>(h, a_src, a_dst, rowse, col, bias, out);
}